// Round 1
// baseline (1541.875 us; speedup 1.0000x reference)
//
#include <hip/hip_runtime.h>
#include <hip/hip_bf16.h>

#define B_ 4
#define N_ 2048
#define D_ 768
#define H_ 12
#define DH_ 64
#define ROWS_ (B_*N_)      // 8192
#define E3_ (3*D_)         // 2304

typedef __hip_bfloat16 bf16;

__device__ __forceinline__ float bfu2f(unsigned short u){
  union{unsigned int i; float f;} c; c.i = ((unsigned int)u) << 16; return c.f;
}
__device__ __forceinline__ bf16 f2b(float f){ return __float2bfloat16(f); }

// ---------------- 1) LayerNorm: x (fp32) -> xn (bf16) ----------------
__global__ __launch_bounds__(256) void ln_kernel(const float* __restrict__ x,
    const float* __restrict__ g, const float* __restrict__ be, bf16* __restrict__ xn){
  int row = blockIdx.x;
  const float* xr = x + (size_t)row * D_;
  int t = threadIdx.x;
  float v0 = xr[t], v1 = xr[t+256], v2 = xr[t+512];
  float s = v0+v1+v2, ss = v0*v0+v1*v1+v2*v2;
  #pragma unroll
  for(int off=32; off; off>>=1){
    s  += __shfl_down(s,  off, 64);
    ss += __shfl_down(ss, off, 64);
  }
  __shared__ float red[2][4];
  int lane = t & 63, wv = t >> 6;
  if(lane==0){ red[0][wv]=s; red[1][wv]=ss; }
  __syncthreads();
  s  = red[0][0]+red[0][1]+red[0][2]+red[0][3];
  ss = red[1][0]+red[1][1]+red[1][2]+red[1][3];
  float mean = s * (1.0f/D_);
  float var  = ss * (1.0f/D_) - mean*mean;
  float rstd = rsqrtf(var + 1e-5f);
  bf16* xo = xn + (size_t)row * D_;
  xo[t]     = f2b((v0-mean)*rstd*g[t]     + be[t]);
  xo[t+256] = f2b((v1-mean)*rstd*g[t+256] + be[t+256]);
  xo[t+512] = f2b((v2-mean)*rstd*g[t+512] + be[t+512]);
}

// ---------------- 2) QKV GEMM: qkv[r][e] = sum_d xn[r][d]*Wqkv[e][d] ----------------
// writes Q,K,V as bf16 in [b][h][n][64] layout
__global__ __launch_bounds__(256) void qkv_gemm(const bf16* __restrict__ A,
    const float* __restrict__ W, bf16* __restrict__ Q, bf16* __restrict__ Kt, bf16* __restrict__ V){
  __shared__ float sA[16][64];
  __shared__ float sB[16][64];
  int row0 = blockIdx.y * 64;
  int e0   = blockIdx.x * 64;
  int tid = threadIdx.x;
  int tx = tid & 15, ty = tid >> 4;
  int lr = tid >> 2;           // 0..63
  int lk = (tid & 3) * 4;      // 0,4,8,12
  float acc[4][4] = {};
  const bf16*  ap = A + (size_t)(row0+lr)*D_ + lk;
  const float* bp = W + (size_t)(e0 +lr)*D_ + lk;
  for(int k0=0; k0<D_; k0+=16){
    union{unsigned long long u; unsigned short us[4];} av;
    av.u = *(const unsigned long long*)(ap + k0);
    float4 bv = *(const float4*)(bp + k0);
    __syncthreads();
    sA[lk+0][lr]=bfu2f(av.us[0]); sA[lk+1][lr]=bfu2f(av.us[1]);
    sA[lk+2][lr]=bfu2f(av.us[2]); sA[lk+3][lr]=bfu2f(av.us[3]);
    sB[lk+0][lr]=bv.x; sB[lk+1][lr]=bv.y; sB[lk+2][lr]=bv.z; sB[lk+3][lr]=bv.w;
    __syncthreads();
    #pragma unroll
    for(int kk=0; kk<16; ++kk){
      float4 a = *(const float4*)&sA[kk][ty*4];
      float4 b = *(const float4*)&sB[kk][tx*4];
      const float* af = (const float*)&a;
      const float* bf = (const float*)&b;
      #pragma unroll
      for(int i=0;i<4;++i)
        #pragma unroll
        for(int j=0;j<4;++j)
          acc[i][j] += af[i]*bf[j];
    }
  }
  int part = e0 / D_;
  int w_   = e0 % D_;
  int h    = w_ >> 6;          // e0 is a multiple of 64 -> whole tile is one head
  bf16* dst = (part==0) ? Q : ((part==1) ? Kt : V);
  #pragma unroll
  for(int i=0;i<4;++i){
    int r = row0 + ty*4 + i;
    int b = r >> 11, n = r & 2047;
    bf16* p = dst + (((size_t)b*H_ + h)*N_ + n)*DH_ + tx*4;
    #pragma unroll
    for(int j=0;j<4;++j) p[j] = f2b(acc[i][j]);
  }
}

// ---------------- 3) RoPE (2 axes, 32 dims each, half=16) on Q and K, in place ----------------
__global__ __launch_bounds__(256) void rope_kernel(bf16* __restrict__ Q, bf16* __restrict__ K,
    const float* __restrict__ coords){
  int t = blockIdx.x*256 + threadIdx.x;    // 0 .. 2*B*H*N-1
  const int total = B_*H_*N_;
  bf16* basep; int idx;
  if (t < total){ basep = Q; idx = t; } else { basep = K; idx = t - total; }
  int n  = idx % N_;
  int bh = idx / N_;
  int b  = bh / H_;
  float c0 = coords[((size_t)b*N_+n)*2 + 0];
  float c1 = coords[((size_t)b*N_+n)*2 + 1];
  bf16* rowp = basep + (size_t)idx * DH_;
  #pragma unroll
  for(int ax=0; ax<2; ++ax){
    float coord = ax ? c1 : c0;
    int base = ax*32;
    float tv[32];
    #pragma unroll
    for(int i=0;i<32;++i) tv[i] = __bfloat162float(rowp[base+i]);
    #pragma unroll
    for(int m=0;m<16;++m){
      float fr = exp2f((float)m * (-13.0f/16.0f));  // 8192^(-m/16), 8192 = 2^13
      float ph = coord * fr;
      float sn, cs;
      sincosf(ph, &sn, &cs);
      rowp[base+m]    = f2b(tv[2*m]*cs - tv[2*m+1]*sn);
      rowp[base+16+m] = f2b(tv[2*m]*sn + tv[2*m+1]*cs);
    }
  }
}

// ---------------- 4) Flash attention, fp32 compute ----------------
__device__ __forceinline__ void load_tile64(const bf16* __restrict__ src, float (*dst)[68], int tid){
  int r = tid >> 2, cs = (tid & 3) * 16;
  const bf16* p = src + r*DH_ + cs;
  #pragma unroll
  for(int j=0;j<16;j+=4){
    union{unsigned long long u; unsigned short us[4];} a;
    a.u = *(const unsigned long long*)(p + j);
    float4 f = make_float4(bfu2f(a.us[0]),bfu2f(a.us[1]),bfu2f(a.us[2]),bfu2f(a.us[3]));
    *(float4*)&dst[r][cs+j] = f;
  }
}

__global__ __launch_bounds__(256) void attn_kernel(const bf16* __restrict__ Q,
    const bf16* __restrict__ K, const bf16* __restrict__ V, bf16* __restrict__ AO){
  __shared__ float sQ [64][68];
  __shared__ float sKP[64][68];   // holds K tile, then reused for P
  __shared__ float sV [64][68];
  __shared__ float sM[64], sL[64], sAl[64];
  int bh = blockIdx.y;
  int q0 = blockIdx.x * 64;
  const bf16* Qp = Q + ((size_t)bh*N_ + q0)*DH_;
  const bf16* Kp = K + (size_t)bh*N_*DH_;
  const bf16* Vp = V + (size_t)bh*N_*DH_;
  int tid = threadIdx.x;
  int tx = tid & 15, ty = tid >> 4;
  load_tile64(Qp, sQ, tid);
  if (tid < 64){ sM[tid] = -1e30f; sL[tid] = 0.0f; }
  float acc[4][4] = {};
  for(int k0=0; k0<N_; k0+=64){
    __syncthreads();                       // prev PV done before tile overwrite
    load_tile64(Kp + (size_t)k0*DH_, sKP, tid);
    load_tile64(Vp + (size_t)k0*DH_, sV,  tid);
    __syncthreads();                       // tiles (and sQ/sM first iter) ready
    // S = Q K^T : thread computes q = ty+16i, k = tx+16j  (conflict-free LDS reads)
    float s[4][4] = {};
    #pragma unroll
    for(int d0=0; d0<64; d0+=4){
      float4 qa[4], kb[4];
      #pragma unroll
      for(int i=0;i<4;++i) qa[i] = *(const float4*)&sQ [ty+16*i][d0];
      #pragma unroll
      for(int j=0;j<4;++j) kb[j] = *(const float4*)&sKP[tx+16*j][d0];
      #pragma unroll
      for(int i=0;i<4;++i){
        const float* qf = (const float*)&qa[i];
        #pragma unroll
        for(int j=0;j<4;++j){
          const float* kf = (const float*)&kb[j];
          s[i][j] += qf[0]*kf[0] + qf[1]*kf[1] + qf[2]*kf[2] + qf[3]*kf[3];
        }
      }
    }
    __syncthreads();                       // everyone done reading K
    #pragma unroll
    for(int i=0;i<4;++i)
      #pragma unroll
      for(int j=0;j<4;++j)
        sKP[ty+16*i][tx+16*j] = s[i][j]*0.125f;   // scale = 1/sqrt(64)
    __syncthreads();                       // P(raw) complete
    // online softmax: 4 threads per row
    {
      int r = tid >> 2, sub = tid & 3;
      float* rowp = &sKP[r][sub*16];
      float vals[16], mx = -1e30f;
      #pragma unroll
      for(int j=0;j<16;++j){ vals[j] = rowp[j]; mx = fmaxf(mx, vals[j]); }
      mx = fmaxf(mx, __shfl_xor(mx, 1, 64));
      mx = fmaxf(mx, __shfl_xor(mx, 2, 64));
      float mold = sM[r];
      float mnew = fmaxf(mold, mx);
      float sum = 0.0f;
      #pragma unroll
      for(int j=0;j<16;++j){ float p = __expf(vals[j]-mnew); rowp[j] = p; sum += p; }
      sum += __shfl_xor(sum, 1, 64);
      sum += __shfl_xor(sum, 2, 64);
      if (sub == 0){
        float al = __expf(mold - mnew);
        sAl[r] = al;
        sL[r]  = sL[r]*al + sum;
        sM[r]  = mnew;
      }
    }
    __syncthreads();                       // P(exp) + alpha ready
    // rescale + PV : thread owns q = ty*4+i, d = tx*4+j
    #pragma unroll
    for(int i=0;i<4;++i){
      float al = sAl[ty*4+i];
      #pragma unroll
      for(int j=0;j<4;++j) acc[i][j] *= al;
    }
    #pragma unroll
    for(int c0=0; c0<64; c0+=4){
      float4 pa[4], vb[4];
      #pragma unroll
      for(int i=0;i<4;++i) pa[i] = *(const float4*)&sKP[ty*4+i][c0];
      #pragma unroll
      for(int c=0;c<4;++c) vb[c] = *(const float4*)&sV[c0+c][tx*4];
      #pragma unroll
      for(int i=0;i<4;++i){
        const float* pf = (const float*)&pa[i];
        #pragma unroll
        for(int j=0;j<4;++j){
          acc[i][j] += pf[0]*((const float*)&vb[0])[j] + pf[1]*((const float*)&vb[1])[j]
                     + pf[2]*((const float*)&vb[2])[j] + pf[3]*((const float*)&vb[3])[j];
        }
      }
    }
  }
  __syncthreads();
  int b = bh / H_, h = bh % H_;
  #pragma unroll
  for(int i=0;i<4;++i){
    int q = ty*4 + i;
    float inv = 1.0f / sL[q];
    bf16* op = AO + ((size_t)b*N_ + q0 + q)*D_ + h*DH_ + tx*4;
    #pragma unroll
    for(int j=0;j<4;++j) op[j] = f2b(acc[i][j]*inv);
  }
}

// ---------------- 5) Output GEMM: out[r][c] = sum_e AO[r][e]*Wout[c][e] ----------------
__global__ __launch_bounds__(256) void out_gemm(const bf16* __restrict__ A,
    const float* __restrict__ W, float* __restrict__ C){
  __shared__ float sA[16][64];
  __shared__ float sB[16][64];
  int row0 = blockIdx.y * 64;
  int c0   = blockIdx.x * 64;
  int tid = threadIdx.x;
  int tx = tid & 15, ty = tid >> 4;
  int lr = tid >> 2;
  int lk = (tid & 3) * 4;
  float acc[4][4] = {};
  const bf16*  ap = A + (size_t)(row0+lr)*D_ + lk;
  const float* bp = W + (size_t)(c0 +lr)*D_ + lk;
  for(int k0=0; k0<D_; k0+=16){
    union{unsigned long long u; unsigned short us[4];} av;
    av.u = *(const unsigned long long*)(ap + k0);
    float4 bv = *(const float4*)(bp + k0);
    __syncthreads();
    sA[lk+0][lr]=bfu2f(av.us[0]); sA[lk+1][lr]=bfu2f(av.us[1]);
    sA[lk+2][lr]=bfu2f(av.us[2]); sA[lk+3][lr]=bfu2f(av.us[3]);
    sB[lk+0][lr]=bv.x; sB[lk+1][lr]=bv.y; sB[lk+2][lr]=bv.z; sB[lk+3][lr]=bv.w;
    __syncthreads();
    #pragma unroll
    for(int kk=0; kk<16; ++kk){
      float4 a = *(const float4*)&sA[kk][ty*4];
      float4 b = *(const float4*)&sB[kk][tx*4];
      const float* af = (const float*)&a;
      const float* bf = (const float*)&b;
      #pragma unroll
      for(int i=0;i<4;++i)
        #pragma unroll
        for(int j=0;j<4;++j)
          acc[i][j] += af[i]*bf[j];
    }
  }
  #pragma unroll
  for(int i=0;i<4;++i){
    int r = row0 + ty*4 + i;
    float* p = C + (size_t)r*D_ + c0 + tx*4;
    #pragma unroll
    for(int j=0;j<4;++j) p[j] = acc[i][j];
  }
}

extern "C" void kernel_launch(void* const* d_in, const int* in_sizes, int n_in,
                              void* d_out, int out_size, void* d_ws, size_t ws_size,
                              hipStream_t stream) {
  (void)in_sizes; (void)n_in; (void)out_size; (void)ws_size;
  const float* x      = (const float*)d_in[0];
  const float* coords = (const float*)d_in[1];
  const float* g      = (const float*)d_in[2];
  const float* be     = (const float*)d_in[3];
  const float* wqkv   = (const float*)d_in[4];
  const float* wout   = (const float*)d_in[5];
  float* out = (float*)d_out;
  char* ws = (char*)d_ws;
  const size_t SEG = (size_t)ROWS_ * D_ * 2;   // 12,582,912 B
  bf16* xn = (bf16*)(ws + 0*SEG);
  bf16* Q  = (bf16*)(ws + 1*SEG);
  bf16* K  = (bf16*)(ws + 2*SEG);
  bf16* V  = (bf16*)(ws + 3*SEG);
  bf16* AO = (bf16*)(ws + 4*SEG);

  ln_kernel  <<<ROWS_, 256, 0, stream>>>(x, g, be, xn);
  qkv_gemm   <<<dim3(E3_/64, ROWS_/64), 256, 0, stream>>>(xn, wqkv, Q, K, V);
  rope_kernel<<<(2*B_*H_*N_)/256, 256, 0, stream>>>(Q, K, coords);
  attn_kernel<<<dim3(N_/64, B_*H_), 256, 0, stream>>>(Q, K, V, AO);
  out_gemm   <<<dim3(D_/64, ROWS_/64), 256, 0, stream>>>(AO, wout, out);
}

// Round 2
// 892.684 us; speedup vs baseline: 1.7272x; 1.7272x over previous
//
#include <hip/hip_runtime.h>
#include <hip/hip_bf16.h>

#define B_ 4
#define N_ 2048
#define D_ 768
#define H_ 12
#define DH_ 64
#define ROWS_ (B_*N_)      // 8192
#define E3_ (3*D_)         // 2304

typedef __hip_bfloat16 bf16;
typedef __attribute__((ext_vector_type(8))) short short8;
typedef __attribute__((ext_vector_type(4))) float floatx4;

__device__ __forceinline__ float bfu2f(unsigned short u){
  union{unsigned int i; float f;} c; c.i = ((unsigned int)u) << 16; return c.f;
}
__device__ __forceinline__ bf16 f2b(float f){ return __float2bfloat16(f); }

// ---------------- 1) LayerNorm: x (fp32) -> xn (bf16) ----------------
__global__ __launch_bounds__(256) void ln_kernel(const float* __restrict__ x,
    const float* __restrict__ g, const float* __restrict__ be, bf16* __restrict__ xn){
  int row = blockIdx.x;
  const float* xr = x + (size_t)row * D_;
  int t = threadIdx.x;
  float v0 = xr[t], v1 = xr[t+256], v2 = xr[t+512];
  float s = v0+v1+v2, ss = v0*v0+v1*v1+v2*v2;
  #pragma unroll
  for(int off=32; off; off>>=1){
    s  += __shfl_down(s,  off, 64);
    ss += __shfl_down(ss, off, 64);
  }
  __shared__ float red[2][4];
  int lane = t & 63, wv = t >> 6;
  if(lane==0){ red[0][wv]=s; red[1][wv]=ss; }
  __syncthreads();
  s  = red[0][0]+red[0][1]+red[0][2]+red[0][3];
  ss = red[1][0]+red[1][1]+red[1][2]+red[1][3];
  float mean = s * (1.0f/D_);
  float var  = ss * (1.0f/D_) - mean*mean;
  float rstd = rsqrtf(var + 1e-5f);
  bf16* xo = xn + (size_t)row * D_;
  xo[t]     = f2b((v0-mean)*rstd*g[t]     + be[t]);
  xo[t+256] = f2b((v1-mean)*rstd*g[t+256] + be[t+256]);
  xo[t+512] = f2b((v2-mean)*rstd*g[t+512] + be[t+512]);
}

// ---------------- 2) QKV GEMM: qkv[r][e] = sum_d xn[r][d]*Wqkv[e][d] ----------------
__global__ __launch_bounds__(256) void qkv_gemm(const bf16* __restrict__ A,
    const float* __restrict__ W, bf16* __restrict__ Q, bf16* __restrict__ Kt, bf16* __restrict__ V){
  __shared__ float sA[16][64];
  __shared__ float sB[16][64];
  int row0 = blockIdx.y * 64;
  int e0   = blockIdx.x * 64;
  int tid = threadIdx.x;
  int tx = tid & 15, ty = tid >> 4;
  int lr = tid >> 2;           // 0..63
  int lk = (tid & 3) * 4;      // 0,4,8,12
  float acc[4][4] = {};
  const bf16*  ap = A + (size_t)(row0+lr)*D_ + lk;
  const float* bp = W + (size_t)(e0 +lr)*D_ + lk;
  for(int k0=0; k0<D_; k0+=16){
    union{unsigned long long u; unsigned short us[4];} av;
    av.u = *(const unsigned long long*)(ap + k0);
    float4 bv = *(const float4*)(bp + k0);
    __syncthreads();
    sA[lk+0][lr]=bfu2f(av.us[0]); sA[lk+1][lr]=bfu2f(av.us[1]);
    sA[lk+2][lr]=bfu2f(av.us[2]); sA[lk+3][lr]=bfu2f(av.us[3]);
    sB[lk+0][lr]=bv.x; sB[lk+1][lr]=bv.y; sB[lk+2][lr]=bv.z; sB[lk+3][lr]=bv.w;
    __syncthreads();
    #pragma unroll
    for(int kk=0; kk<16; ++kk){
      float4 a = *(const float4*)&sA[kk][ty*4];
      float4 b = *(const float4*)&sB[kk][tx*4];
      const float* af = (const float*)&a;
      const float* bf = (const float*)&b;
      #pragma unroll
      for(int i=0;i<4;++i)
        #pragma unroll
        for(int j=0;j<4;++j)
          acc[i][j] += af[i]*bf[j];
    }
  }
  int part = e0 / D_;
  int w_   = e0 % D_;
  int h    = w_ >> 6;
  bf16* dst = (part==0) ? Q : ((part==1) ? Kt : V);
  #pragma unroll
  for(int i=0;i<4;++i){
    int r = row0 + ty*4 + i;
    int b = r >> 11, n = r & 2047;
    bf16* p = dst + (((size_t)b*H_ + h)*N_ + n)*DH_ + tx*4;
    #pragma unroll
    for(int j=0;j<4;++j) p[j] = f2b(acc[i][j]);
  }
}

// ---------------- 3) RoPE (2 axes, 32 dims each, half=16) on Q and K, in place ----------------
__global__ __launch_bounds__(256) void rope_kernel(bf16* __restrict__ Q, bf16* __restrict__ K,
    const float* __restrict__ coords){
  int t = blockIdx.x*256 + threadIdx.x;
  const int total = B_*H_*N_;
  bf16* basep; int idx;
  if (t < total){ basep = Q; idx = t; } else { basep = K; idx = t - total; }
  int n  = idx % N_;
  int bh = idx / N_;
  int b  = bh / H_;
  float c0 = coords[((size_t)b*N_+n)*2 + 0];
  float c1 = coords[((size_t)b*N_+n)*2 + 1];
  bf16* rowp = basep + (size_t)idx * DH_;
  #pragma unroll
  for(int ax=0; ax<2; ++ax){
    float coord = ax ? c1 : c0;
    int base = ax*32;
    float tv[32];
    #pragma unroll
    for(int i=0;i<32;++i) tv[i] = __bfloat162float(rowp[base+i]);
    #pragma unroll
    for(int m=0;m<16;++m){
      float fr = exp2f((float)m * (-13.0f/16.0f));
      float ph = coord * fr;
      float sn, cs;
      sincosf(ph, &sn, &cs);
      rowp[base+m]    = f2b(tv[2*m]*cs - tv[2*m+1]*sn);
      rowp[base+16+m] = f2b(tv[2*m]*sn + tv[2*m+1]*cs);
    }
  }
}

// ---------------- 4) Flash attention, MFMA bf16 ----------------
// Per block: one (b,h), 64 q rows. 4 waves; wave w owns q-strip [16w,16w+16).
// S = Q·K^T via mfma (A=Q frag, B=K rows frag, both loaded straight from global).
// Softmax in registers (C/D layout: row=quad*4+reg, col=lane&15 + 16*nt).
// PV as O^T = V^T · P^T: A = V^T (8 scalar global loads/lane, 2 frags/wave/iter),
// B = P^T (contiguous 16B reads from LDS P). Epilogue transposes O^T via LDS.
#define PITCH_ 72
__global__ __launch_bounds__(256) void attn_kernel(const bf16* __restrict__ Q,
    const bf16* __restrict__ K, const bf16* __restrict__ V, bf16* __restrict__ AO){
  __shared__ bf16 sP[64*PITCH_];
  __shared__ float sAl[64];
  __shared__ float sL[64];
  int bh = blockIdx.y;
  int q0 = blockIdx.x * 64;
  int tid = threadIdx.x;
  int w = tid >> 6, lane = tid & 63, quad = lane >> 4, l15 = lane & 15;
  const bf16* Qb = Q + (size_t)bh*N_*DH_;
  const short* Ks = (const short*)(K + (size_t)bh*N_*DH_);
  const short* Vs = (const short*)(V + (size_t)bh*N_*DH_);

  // Q fragments for this wave's q-strip (A-operand layout: m=l15, k=quad*8+j)
  const short* qrow = (const short*)(Qb + (size_t)(q0 + 16*w + l15)*DH_ + quad*8);
  short8 qf0 = *(const short8*)(qrow);
  short8 qf1 = *(const short8*)(qrow + 32);

  float m_prev[4], l_run[4];
  #pragma unroll
  for(int r=0;r<4;++r){ m_prev[r] = -1e30f; l_run[r] = 0.0f; }
  floatx4 acc[4];
  #pragma unroll
  for(int qt=0;qt<4;++qt) acc[qt] = (floatx4){0.f,0.f,0.f,0.f};

  for(int kv0=0; kv0<N_; kv0+=64){
    __syncthreads();                          // prev-iter sP reads complete
    // ---- S = Q K^T  (wave strip: rows 16w.., cols kv0..kv0+63) ----
    floatx4 s[4];
    #pragma unroll
    for(int nt=0; nt<4; ++nt){
      const short* krow = Ks + (size_t)(kv0 + 16*nt + l15)*DH_ + quad*8;
      short8 kf0 = *(const short8*)(krow);
      short8 kf1 = *(const short8*)(krow + 32);
      floatx4 z = {0.f,0.f,0.f,0.f};
      z = __builtin_amdgcn_mfma_f32_16x16x32_bf16(qf0, kf0, z, 0, 0, 0);
      z = __builtin_amdgcn_mfma_f32_16x16x32_bf16(qf1, kf1, z, 0, 0, 0);
      s[nt] = z;
    }
    // ---- online softmax (per-quad rows quad*4+r; cols spread over l15 and nt) ----
    #pragma unroll
    for(int nt=0;nt<4;++nt)
      #pragma unroll
      for(int r=0;r<4;++r) s[nt][r] *= 0.125f;      // 1/sqrt(64)
    float mx[4], alpha[4], rs[4];
    #pragma unroll
    for(int r=0;r<4;++r){
      mx[r] = fmaxf(fmaxf(s[0][r], s[1][r]), fmaxf(s[2][r], s[3][r]));
    }
    #pragma unroll
    for(int off=1; off<16; off<<=1){
      #pragma unroll
      for(int r=0;r<4;++r) mx[r] = fmaxf(mx[r], __shfl_xor(mx[r], off, 64));
    }
    #pragma unroll
    for(int r=0;r<4;++r){
      float mnew = fmaxf(m_prev[r], mx[r]);
      alpha[r] = __expf(m_prev[r] - mnew);
      m_prev[r] = mnew;
      rs[r] = 0.0f;
    }
    #pragma unroll
    for(int nt=0;nt<4;++nt){
      #pragma unroll
      for(int r=0;r<4;++r){
        float p = __expf(s[nt][r] - m_prev[r]);
        s[nt][r] = p;
        rs[r] += p;
      }
    }
    #pragma unroll
    for(int off=1; off<16; off<<=1){
      #pragma unroll
      for(int r=0;r<4;++r) rs[r] += __shfl_xor(rs[r], off, 64);
    }
    #pragma unroll
    for(int r=0;r<4;++r) l_run[r] = l_run[r]*alpha[r] + rs[r];
    // write P (bf16) to LDS; rows of own strip only
    #pragma unroll
    for(int nt=0;nt<4;++nt)
      #pragma unroll
      for(int r=0;r<4;++r)
        sP[(16*w + quad*4 + r)*PITCH_ + l15 + 16*nt] = f2b(s[nt][r]);
    #pragma unroll
    for(int r=0;r<4;++r) if (l15 == r) sAl[16*w + quad*4 + r] = alpha[r];
    __syncthreads();                          // sP + sAl published
    // ---- rescale O^T acc (col = q = l15 + 16qt) ----
    #pragma unroll
    for(int qt=0;qt<4;++qt){
      float a = sAl[l15 + 16*qt];
      #pragma unroll
      for(int r=0;r<4;++r) acc[qt][r] *= a;
    }
    // ---- O^T += V^T · P^T ----
    #pragma unroll
    for(int t=0;t<2;++t){
      short8 vf;
      #pragma unroll
      for(int j=0;j<8;++j)
        ((short*)&vf)[j] = Vs[(size_t)(kv0 + 32*t + quad*8 + j)*DH_ + 16*w + l15];
      #pragma unroll
      for(int qt=0;qt<4;++qt){
        short8 pf = *(const short8*)&sP[(l15 + 16*qt)*PITCH_ + quad*8 + 32*t];
        acc[qt] = __builtin_amdgcn_mfma_f32_16x16x32_bf16(vf, pf, acc[qt], 0, 0, 0);
      }
    }
  }
  // ---- epilogue: divide by l, transpose O^T -> O via LDS, coalesced store ----
  #pragma unroll
  for(int r=0;r<4;++r) if (l15 == r) sL[16*w + quad*4 + r] = l_run[r];
  __syncthreads();                            // last sP reads done + sL ready
  bf16* sO = sP;
  #pragma unroll
  for(int qt=0;qt<4;++qt){
    float inv = 1.0f / sL[l15 + 16*qt];
    #pragma unroll
    for(int r=0;r<4;++r)
      sO[(l15 + 16*qt)*PITCH_ + 16*w + quad*4 + r] = f2b(acc[qt][r]*inv);
  }
  __syncthreads();
  int rr = tid >> 2, cc = (tid & 3) * 16;
  int b = bh / H_, h = bh % H_;
  bf16* op = AO + ((size_t)(b*N_ + q0 + rr))*D_ + h*DH_ + cc;
  short8 o0 = *(const short8*)&sO[rr*PITCH_ + cc];
  short8 o1 = *(const short8*)&sO[rr*PITCH_ + cc + 8];
  *(short8*)(op)     = o0;
  *(short8*)(op + 8) = o1;
}

// ---------------- 5) Output GEMM: out[r][c] = sum_e AO[r][e]*Wout[c][e] ----------------
__global__ __launch_bounds__(256) void out_gemm(const bf16* __restrict__ A,
    const float* __restrict__ W, float* __restrict__ C){
  __shared__ float sA[16][64];
  __shared__ float sB[16][64];
  int row0 = blockIdx.y * 64;
  int c0   = blockIdx.x * 64;
  int tid = threadIdx.x;
  int tx = tid & 15, ty = tid >> 4;
  int lr = tid >> 2;
  int lk = (tid & 3) * 4;
  float acc[4][4] = {};
  const bf16*  ap = A + (size_t)(row0+lr)*D_ + lk;
  const float* bp = W + (size_t)(c0 +lr)*D_ + lk;
  for(int k0=0; k0<D_; k0+=16){
    union{unsigned long long u; unsigned short us[4];} av;
    av.u = *(const unsigned long long*)(ap + k0);
    float4 bv = *(const float4*)(bp + k0);
    __syncthreads();
    sA[lk+0][lr]=bfu2f(av.us[0]); sA[lk+1][lr]=bfu2f(av.us[1]);
    sA[lk+2][lr]=bfu2f(av.us[2]); sA[lk+3][lr]=bfu2f(av.us[3]);
    sB[lk+0][lr]=bv.x; sB[lk+1][lr]=bv.y; sB[lk+2][lr]=bv.z; sB[lk+3][lr]=bv.w;
    __syncthreads();
    #pragma unroll
    for(int kk=0; kk<16; ++kk){
      float4 a = *(const float4*)&sA[kk][ty*4];
      float4 b = *(const float4*)&sB[kk][tx*4];
      const float* af = (const float*)&a;
      const float* bf = (const float*)&b;
      #pragma unroll
      for(int i=0;i<4;++i)
        #pragma unroll
        for(int j=0;j<4;++j)
          acc[i][j] += af[i]*bf[j];
    }
  }
  #pragma unroll
  for(int i=0;i<4;++i){
    int r = row0 + ty*4 + i;
    float* p = C + (size_t)r*D_ + c0 + tx*4;
    #pragma unroll
    for(int j=0;j<4;++j) p[j] = acc[i][j];
  }
}

extern "C" void kernel_launch(void* const* d_in, const int* in_sizes, int n_in,
                              void* d_out, int out_size, void* d_ws, size_t ws_size,
                              hipStream_t stream) {
  (void)in_sizes; (void)n_in; (void)out_size; (void)ws_size;
  const float* x      = (const float*)d_in[0];
  const float* coords = (const float*)d_in[1];
  const float* g      = (const float*)d_in[2];
  const float* be     = (const float*)d_in[3];
  const float* wqkv   = (const float*)d_in[4];
  const float* wout   = (const float*)d_in[5];
  float* out = (float*)d_out;
  char* ws = (char*)d_ws;
  const size_t SEG = (size_t)ROWS_ * D_ * 2;
  bf16* xn = (bf16*)(ws + 0*SEG);
  bf16* Q  = (bf16*)(ws + 1*SEG);
  bf16* K  = (bf16*)(ws + 2*SEG);
  bf16* V  = (bf16*)(ws + 3*SEG);
  bf16* AO = (bf16*)(ws + 4*SEG);

  ln_kernel  <<<ROWS_, 256, 0, stream>>>(x, g, be, xn);
  qkv_gemm   <<<dim3(E3_/64, ROWS_/64), 256, 0, stream>>>(xn, wqkv, Q, K, V);
  rope_kernel<<<(2*B_*H_*N_)/256, 256, 0, stream>>>(Q, K, coords);
  attn_kernel<<<dim3(N_/64, B_*H_), 256, 0, stream>>>(Q, K, V, AO);
  out_gemm   <<<dim3(D_/64, ROWS_/64), 256, 0, stream>>>(AO, wout, out);
}

// Round 3
// 464.961 us; speedup vs baseline: 3.3161x; 1.9199x over previous
//
#include <hip/hip_runtime.h>

#define B_ 4
#define N_ 2048
#define D_ 768
#define H_ 12
#define DH_ 64
#define ROWS_ (B_*N_)      // 8192
#define E3_ (3*D_)         // 2304

typedef _Float16 f16;
typedef __attribute__((ext_vector_type(8))) _Float16 half8;
typedef __attribute__((ext_vector_type(4))) float floatx4;

__device__ __forceinline__ void gload_lds16(const void* g, void* lds){
  __builtin_amdgcn_global_load_lds(
      (const __attribute__((address_space(1))) unsigned int*)g,
      (__attribute__((address_space(3))) unsigned int*)lds, 16, 0, 0);
}

// ---------------- 0) fp32 -> fp16 weight convert ----------------
__global__ __launch_bounds__(256) void cvt_kernel(const float* __restrict__ src,
    f16* __restrict__ dst, int n8){
  int i = blockIdx.x*256 + threadIdx.x;
  if (i < n8){
    float4 a = ((const float4*)src)[2*i];
    float4 b = ((const float4*)src)[2*i+1];
    half8 h;
    h[0]=(f16)a.x; h[1]=(f16)a.y; h[2]=(f16)a.z; h[3]=(f16)a.w;
    h[4]=(f16)b.x; h[5]=(f16)b.y; h[6]=(f16)b.z; h[7]=(f16)b.w;
    *(half8*)(dst + (size_t)i*8) = h;
  }
}

// ---------------- 1) LayerNorm: x (fp32) -> xn (fp16) ----------------
__global__ __launch_bounds__(256) void ln_kernel(const float* __restrict__ x,
    const float* __restrict__ g, const float* __restrict__ be, f16* __restrict__ xn){
  int row = blockIdx.x;
  const float* xr = x + (size_t)row * D_;
  int t = threadIdx.x;
  float v0 = xr[t], v1 = xr[t+256], v2 = xr[t+512];
  float s = v0+v1+v2, ss = v0*v0+v1*v1+v2*v2;
  #pragma unroll
  for(int off=32; off; off>>=1){
    s  += __shfl_down(s,  off, 64);
    ss += __shfl_down(ss, off, 64);
  }
  __shared__ float red[2][4];
  int lane = t & 63, wv = t >> 6;
  if(lane==0){ red[0][wv]=s; red[1][wv]=ss; }
  __syncthreads();
  s  = red[0][0]+red[0][1]+red[0][2]+red[0][3];
  ss = red[1][0]+red[1][1]+red[1][2]+red[1][3];
  float mean = s * (1.0f/D_);
  float var  = ss * (1.0f/D_) - mean*mean;
  float rstd = rsqrtf(var + 1e-5f);
  f16* xo = xn + (size_t)row * D_;
  xo[t]     = (f16)((v0-mean)*rstd*g[t]     + be[t]);
  xo[t+256] = (f16)((v1-mean)*rstd*g[t+256] + be[t+256]);
  xo[t+512] = (f16)((v2-mean)*rstd*g[t+512] + be[t+512]);
}

// ---------------- 2) QKV GEMM (MFMA): qkv[r][e] = sum_d xn[r][d]*W16[e][d] ----------------
// 128x128 tile, BK=32, 4 waves in 2x2; global_load_lds staging, scatter epilogue to Q/K/V.
__global__ __launch_bounds__(256) void qkv_gemm(const f16* __restrict__ A,
    const f16* __restrict__ W, f16* __restrict__ Q, f16* __restrict__ Kt, f16* __restrict__ V){
  __shared__ f16 sA[128*32];
  __shared__ f16 sB[128*32];
  int tid = threadIdx.x;
  int w = tid >> 6, lane = tid & 63, quad = lane >> 4, l15 = lane & 15;
  int row0 = blockIdx.y * 128;
  int e0   = blockIdx.x * 128;
  int wr = (w >> 1) * 64, wc = (w & 1) * 64;
  // staging chunk mapping: chunk c covers row=c>>2, col-chunk=(c&3)*8 (16B)
  int r0c = tid >> 2,        ci0 = (tid & 3) * 8;
  int r1c = (256+tid) >> 2,  ci1 = (tid & 3) * 8;
  floatx4 acc[4][4];
  #pragma unroll
  for(int i=0;i<4;++i)
    #pragma unroll
    for(int j=0;j<4;++j) acc[i][j] = (floatx4){0.f,0.f,0.f,0.f};

  for(int k0=0; k0<D_; k0+=32){
    __syncthreads();
    gload_lds16(A + (size_t)(row0+r0c)*D_ + k0 + ci0, sA + (size_t)(w*64)*8);
    gload_lds16(A + (size_t)(row0+r1c)*D_ + k0 + ci1, sA + (size_t)(256 + w*64)*8);
    gload_lds16(W + (size_t)(e0 +r0c)*D_ + k0 + ci0, sB + (size_t)(w*64)*8);
    gload_lds16(W + (size_t)(e0 +r1c)*D_ + k0 + ci1, sB + (size_t)(256 + w*64)*8);
    __syncthreads();
    half8 af[4], bf[4];
    #pragma unroll
    for(int mi=0;mi<4;++mi) af[mi] = *(const half8*)&sA[(wr + mi*16 + l15)*32 + quad*8];
    #pragma unroll
    for(int ni=0;ni<4;++ni) bf[ni] = *(const half8*)&sB[(wc + ni*16 + l15)*32 + quad*8];
    #pragma unroll
    for(int mi=0;mi<4;++mi)
      #pragma unroll
      for(int ni=0;ni<4;++ni)
        acc[mi][ni] = __builtin_amdgcn_mfma_f32_16x16x32_f16(af[mi], bf[ni], acc[mi][ni], 0, 0, 0);
  }
  // epilogue: e0 block (128 cols) lies in one part (768%128==0)
  int part = e0 / D_;
  int erel = e0 % D_;
  f16* dst = (part==0) ? Q : ((part==1) ? Kt : V);
  #pragma unroll
  for(int ni=0;ni<4;++ni){
    int col = erel + wc + ni*16 + l15;
    int h = col >> 6, d = col & 63;
    #pragma unroll
    for(int mi=0;mi<4;++mi){
      int rbase = row0 + wr + mi*16 + quad*4;
      #pragma unroll
      for(int reg=0;reg<4;++reg){
        int r = rbase + reg;
        int b = r >> 11, n = r & 2047;
        dst[(((size_t)b*H_ + h)*N_ + n)*DH_ + d] = (f16)acc[mi][ni][reg];
      }
    }
  }
}

// ---------------- 3) RoPE (2 axes, 32 dims each, half=16) on Q and K, in place ----------------
__global__ __launch_bounds__(256) void rope_kernel(f16* __restrict__ Q, f16* __restrict__ K,
    const float* __restrict__ coords){
  int t = blockIdx.x*256 + threadIdx.x;
  const int total = B_*H_*N_;
  f16* basep; int idx;
  if (t < total){ basep = Q; idx = t; } else { basep = K; idx = t - total; }
  int n  = idx % N_;
  int bh = idx / N_;
  int b  = bh / H_;
  float c0 = coords[((size_t)b*N_+n)*2 + 0];
  float c1 = coords[((size_t)b*N_+n)*2 + 1];
  f16* rowp = basep + (size_t)idx * DH_;
  #pragma unroll
  for(int ax=0; ax<2; ++ax){
    float coord = ax ? c1 : c0;
    int base = ax*32;
    float tv[32];
    #pragma unroll
    for(int i=0;i<32;++i) tv[i] = (float)rowp[base+i];
    #pragma unroll
    for(int m=0;m<16;++m){
      float fr = exp2f((float)m * (-13.0f/16.0f));
      float ph = coord * fr;
      float sn, cs;
      sincosf(ph, &sn, &cs);
      rowp[base+m]    = (f16)(tv[2*m]*cs - tv[2*m+1]*sn);
      rowp[base+16+m] = (f16)(tv[2*m]*sn + tv[2*m+1]*cs);
    }
  }
}

// ---------------- 4) Flash attention, MFMA fp16 ----------------
#define PITCH_ 72
__global__ __launch_bounds__(256) void attn_kernel(const f16* __restrict__ Q,
    const f16* __restrict__ K, const f16* __restrict__ V, f16* __restrict__ AO){
  __shared__ f16 sP[64*PITCH_];
  __shared__ float sAl[64];
  __shared__ float sL[64];
  int bh = blockIdx.y;
  int q0 = blockIdx.x * 64;
  int tid = threadIdx.x;
  int w = tid >> 6, lane = tid & 63, quad = lane >> 4, l15 = lane & 15;
  const f16* Qb = Q + (size_t)bh*N_*DH_;
  const f16* Ks = K + (size_t)bh*N_*DH_;
  const f16* Vs = V + (size_t)bh*N_*DH_;

  const f16* qrow = Qb + (size_t)(q0 + 16*w + l15)*DH_ + quad*8;
  half8 qf0 = *(const half8*)(qrow);
  half8 qf1 = *(const half8*)(qrow + 32);

  float m_prev[4], l_run[4];
  #pragma unroll
  for(int r=0;r<4;++r){ m_prev[r] = -1e30f; l_run[r] = 0.0f; }
  floatx4 acc[4];
  #pragma unroll
  for(int qt=0;qt<4;++qt) acc[qt] = (floatx4){0.f,0.f,0.f,0.f};

  for(int kv0=0; kv0<N_; kv0+=64){
    __syncthreads();                          // prev-iter sP reads complete
    floatx4 s[4];
    #pragma unroll
    for(int nt=0; nt<4; ++nt){
      const f16* krow = Ks + (size_t)(kv0 + 16*nt + l15)*DH_ + quad*8;
      half8 kf0 = *(const half8*)(krow);
      half8 kf1 = *(const half8*)(krow + 32);
      floatx4 z = {0.f,0.f,0.f,0.f};
      z = __builtin_amdgcn_mfma_f32_16x16x32_f16(qf0, kf0, z, 0, 0, 0);
      z = __builtin_amdgcn_mfma_f32_16x16x32_f16(qf1, kf1, z, 0, 0, 0);
      s[nt] = z;
    }
    #pragma unroll
    for(int nt=0;nt<4;++nt)
      #pragma unroll
      for(int r=0;r<4;++r) s[nt][r] *= 0.125f;
    float mx[4], alpha[4], rs[4];
    #pragma unroll
    for(int r=0;r<4;++r)
      mx[r] = fmaxf(fmaxf(s[0][r], s[1][r]), fmaxf(s[2][r], s[3][r]));
    #pragma unroll
    for(int off=1; off<16; off<<=1){
      #pragma unroll
      for(int r=0;r<4;++r) mx[r] = fmaxf(mx[r], __shfl_xor(mx[r], off, 64));
    }
    #pragma unroll
    for(int r=0;r<4;++r){
      float mnew = fmaxf(m_prev[r], mx[r]);
      alpha[r] = __expf(m_prev[r] - mnew);
      m_prev[r] = mnew;
      rs[r] = 0.0f;
    }
    #pragma unroll
    for(int nt=0;nt<4;++nt){
      #pragma unroll
      for(int r=0;r<4;++r){
        float p = __expf(s[nt][r] - m_prev[r]);
        s[nt][r] = p;
        rs[r] += p;
      }
    }
    #pragma unroll
    for(int off=1; off<16; off<<=1){
      #pragma unroll
      for(int r=0;r<4;++r) rs[r] += __shfl_xor(rs[r], off, 64);
    }
    #pragma unroll
    for(int r=0;r<4;++r) l_run[r] = l_run[r]*alpha[r] + rs[r];
    #pragma unroll
    for(int nt=0;nt<4;++nt)
      #pragma unroll
      for(int r=0;r<4;++r)
        sP[(16*w + quad*4 + r)*PITCH_ + l15 + 16*nt] = (f16)s[nt][r];
    #pragma unroll
    for(int r=0;r<4;++r) if (l15 == r) sAl[16*w + quad*4 + r] = alpha[r];
    __syncthreads();                          // sP + sAl published
    #pragma unroll
    for(int qt=0;qt<4;++qt){
      float a = sAl[l15 + 16*qt];
      #pragma unroll
      for(int r=0;r<4;++r) acc[qt][r] *= a;
    }
    #pragma unroll
    for(int t=0;t<2;++t){
      half8 vf;
      #pragma unroll
      for(int j=0;j<8;++j)
        ((f16*)&vf)[j] = Vs[(size_t)(kv0 + 32*t + quad*8 + j)*DH_ + 16*w + l15];
      #pragma unroll
      for(int qt=0;qt<4;++qt){
        half8 pf = *(const half8*)&sP[(l15 + 16*qt)*PITCH_ + quad*8 + 32*t];
        acc[qt] = __builtin_amdgcn_mfma_f32_16x16x32_f16(vf, pf, acc[qt], 0, 0, 0);
      }
    }
  }
  #pragma unroll
  for(int r=0;r<4;++r) if (l15 == r) sL[16*w + quad*4 + r] = l_run[r];
  __syncthreads();
  f16* sO = sP;
  #pragma unroll
  for(int qt=0;qt<4;++qt){
    float inv = 1.0f / sL[l15 + 16*qt];
    #pragma unroll
    for(int r=0;r<4;++r)
      sO[(l15 + 16*qt)*PITCH_ + 16*w + quad*4 + r] = (f16)(acc[qt][r]*inv);
  }
  __syncthreads();
  int rr = tid >> 2, cc = (tid & 3) * 16;
  int b = bh / H_, h = bh % H_;
  f16* op = AO + ((size_t)(b*N_ + q0 + rr))*D_ + h*DH_ + cc;
  half8 o0 = *(const half8*)&sO[rr*PITCH_ + cc];
  half8 o1 = *(const half8*)&sO[rr*PITCH_ + cc + 8];
  *(half8*)(op)     = o0;
  *(half8*)(op + 8) = o1;
}

// ---------------- 5) Output GEMM (MFMA): out[r][c] = sum_e AO[r][e]*Wo16[c][e] ----------------
__global__ __launch_bounds__(256) void out_gemm(const f16* __restrict__ A,
    const f16* __restrict__ W, float* __restrict__ C){
  __shared__ f16 sA[128*32];
  __shared__ f16 sB[128*32];
  int tid = threadIdx.x;
  int w = tid >> 6, lane = tid & 63, quad = lane >> 4, l15 = lane & 15;
  int row0 = blockIdx.y * 128;
  int e0   = blockIdx.x * 128;
  int wr = (w >> 1) * 64, wc = (w & 1) * 64;
  int r0c = tid >> 2,        ci0 = (tid & 3) * 8;
  int r1c = (256+tid) >> 2,  ci1 = (tid & 3) * 8;
  floatx4 acc[4][4];
  #pragma unroll
  for(int i=0;i<4;++i)
    #pragma unroll
    for(int j=0;j<4;++j) acc[i][j] = (floatx4){0.f,0.f,0.f,0.f};

  for(int k0=0; k0<D_; k0+=32){
    __syncthreads();
    gload_lds16(A + (size_t)(row0+r0c)*D_ + k0 + ci0, sA + (size_t)(w*64)*8);
    gload_lds16(A + (size_t)(row0+r1c)*D_ + k0 + ci1, sA + (size_t)(256 + w*64)*8);
    gload_lds16(W + (size_t)(e0 +r0c)*D_ + k0 + ci0, sB + (size_t)(w*64)*8);
    gload_lds16(W + (size_t)(e0 +r1c)*D_ + k0 + ci1, sB + (size_t)(256 + w*64)*8);
    __syncthreads();
    half8 af[4], bf[4];
    #pragma unroll
    for(int mi=0;mi<4;++mi) af[mi] = *(const half8*)&sA[(wr + mi*16 + l15)*32 + quad*8];
    #pragma unroll
    for(int ni=0;ni<4;++ni) bf[ni] = *(const half8*)&sB[(wc + ni*16 + l15)*32 + quad*8];
    #pragma unroll
    for(int mi=0;mi<4;++mi)
      #pragma unroll
      for(int ni=0;ni<4;++ni)
        acc[mi][ni] = __builtin_amdgcn_mfma_f32_16x16x32_f16(af[mi], bf[ni], acc[mi][ni], 0, 0, 0);
  }
  #pragma unroll
  for(int ni=0;ni<4;++ni){
    int col = e0 + wc + ni*16 + l15;
    #pragma unroll
    for(int mi=0;mi<4;++mi){
      int rbase = row0 + wr + mi*16 + quad*4;
      #pragma unroll
      for(int reg=0;reg<4;++reg)
        C[(size_t)(rbase+reg)*D_ + col] = acc[mi][ni][reg];
    }
  }
}

extern "C" void kernel_launch(void* const* d_in, const int* in_sizes, int n_in,
                              void* d_out, int out_size, void* d_ws, size_t ws_size,
                              hipStream_t stream) {
  (void)in_sizes; (void)n_in; (void)out_size; (void)ws_size;
  const float* x      = (const float*)d_in[0];
  const float* coords = (const float*)d_in[1];
  const float* g      = (const float*)d_in[2];
  const float* be     = (const float*)d_in[3];
  const float* wqkv   = (const float*)d_in[4];
  const float* wout   = (const float*)d_in[5];
  float* out = (float*)d_out;
  char* ws = (char*)d_ws;
  const size_t SEG = (size_t)ROWS_ * D_ * 2;   // 12,582,912 B
  f16* xn  = (f16*)(ws + 0*SEG);
  f16* Q   = (f16*)(ws + 1*SEG);
  f16* K   = (f16*)(ws + 2*SEG);
  f16* V   = (f16*)(ws + 3*SEG);
  f16* AO  = (f16*)(ws + 4*SEG);
  f16* W16 = (f16*)(ws + 5*SEG);                         // 2304*768 fp16
  f16* Wo16= (f16*)(ws + 5*SEG + (size_t)E3_*D_*2);      // 768*768 fp16

  cvt_kernel <<<(E3_*D_/8 + 255)/256, 256, 0, stream>>>(wqkv, W16, E3_*D_/8);
  cvt_kernel <<<(D_*D_/8 + 255)/256, 256, 0, stream>>>(wout, Wo16, D_*D_/8);
  ln_kernel  <<<ROWS_, 256, 0, stream>>>(x, g, be, xn);
  qkv_gemm   <<<dim3(E3_/128, ROWS_/128), 256, 0, stream>>>(xn, W16, Q, K, V);
  rope_kernel<<<(2*B_*H_*N_)/256, 256, 0, stream>>>(Q, K, coords);
  attn_kernel<<<dim3(N_/64, B_*H_), 256, 0, stream>>>(Q, K, V, AO);
  out_gemm   <<<dim3(D_/128, ROWS_/128), 256, 0, stream>>>(AO, Wo16, out);
}